// Round 17
// baseline (219.489 us; speedup 1.0000x reference)
//
#include <hip/hip_runtime.h>
#include <hip/hip_fp16.h>
#include <math.h>

// GCN: CSR via single-pass bucket scatter; gemm0 (MFMA); then 3 FUSED
// agg+MFMA-gemm kernels (gather h in-register -> LDS -> MFMA with next layer's
// W -> T'_{l+1} directly); final agg+softmax. T' fp16.
// out[d] = dinv[d]*(T'[d] + sum_{s in N(d)} T'[s]) + b, T'[i] = dinv[i]*(h[i]@W).

#define BBITS 9
#define BSIZE 512
#define BCAP 10240
#define CHUNK 1024          // R16: halved -> 2x blocks for latency hiding
#define STAGE_CAP 12288

typedef __attribute__((ext_vector_type(8))) _Float16 half8;
typedef __attribute__((ext_vector_type(4))) float f32x4;

// Bucket-scatter into region b*BCAP. Edges held in REGISTERS between hist and
// scatter phases (no dst/src re-read). Plain stores (nontemporal caused 3.4x
// write amplification in R14). Blocks >= nPassA transpose weights to fp16.
__global__ __launch_bounds__(256) void passA_kernel(const int* __restrict__ src, const int* __restrict__ dst,
                                                    int* gCursor, unsigned* __restrict__ pairbuf,
                                                    int nE, int nPassA,
                                                    const float* __restrict__ W0, const float* __restrict__ W1,
                                                    const float* __restrict__ W2, const float* __restrict__ W3,
                                                    __half* __restrict__ Wt0, __half* __restrict__ Wt1,
                                                    __half* __restrict__ Wt2, __half* __restrict__ Wt3) {
    const int t = threadIdx.x;
    if (blockIdx.x >= nPassA) {
        const int b = blockIdx.x - nPassA;   // 0..3
        if (b < 3) {
            const float* W = (b == 0) ? W0 : (b == 1) ? W1 : W2;
            __half* Wt = (b == 0) ? Wt0 : (b == 1) ? Wt1 : Wt2;
            const int K = (b == 0) ? 128 : 64;
            const int tot = 64 * K;
            for (int i = t; i < tot; i += 256) {
                int nn = i / K, k = i - nn * K;
                Wt[i] = (__half)W[k * 64 + nn];
            }
        } else {
            for (int i = t; i < 48 * 64; i += 256) {      // Wt3 [48][64], cols>=40 zero
                int c = i >> 6, k = i & 63;
                Wt3[i] = (c < 40) ? (__half)W3[k * 40 + c] : (__half)0.f;
            }
        }
        return;
    }
    __shared__ int hist[256], base[256], offs[256];
    hist[t] = 0; offs[t] = 0;
    __syncthreads();
    const int e0 = blockIdx.x * CHUNK;
    constexpr int EPT = CHUNK / 256;         // 4 edges per thread, in registers
    int dreg[EPT], sreg[EPT];
    #pragma unroll
    for (int i = 0; i < EPT; ++i) {
        const int e = e0 + i * 256 + t;
        const bool ok = (e < nE);
        dreg[i] = ok ? dst[e] : -1;
        sreg[i] = ok ? src[e] : 0;
        if (ok) atomicAdd(&hist[dreg[i] >> BBITS], 1);
    }
    __syncthreads();
    if (hist[t]) base[t] = atomicAdd(&gCursor[t], hist[t]);
    __syncthreads();
    #pragma unroll
    for (int i = 0; i < EPT; ++i) {
        if (dreg[i] >= 0) {
            const int b = dreg[i] >> BBITS;
            const int pos = b * BCAP + base[b] + atomicAdd(&offs[b], 1);
            pairbuf[pos] = (unsigned)sreg[i] | ((unsigned)(dreg[i] & (BSIZE - 1)) << 17);
        }
    }
}

// Per-bucket: stage pairs, LDS count, scan, write rowbeg/rowend/dinv, place adj.
__global__ __launch_bounds__(256) void passB_kernel(const unsigned* __restrict__ pairbuf, const int* __restrict__ gCursor,
                                                    int* __restrict__ rowbeg, int* __restrict__ rowend,
                                                    float* __restrict__ dinv, int* __restrict__ adj, int n) {
    __shared__ unsigned stage[STAGE_CAP];
    __shared__ int cnt[BSIZE], rb[BSIZE], cur[BSIZE];
    __shared__ int sb[256];
    const int t = threadIdx.x;
    const int b = blockIdx.x;
    const int pBeg = b * BCAP;
    const int m = gCursor[b];
    cnt[t] = 0; cnt[t + 256] = 0; cur[t] = 0; cur[t + 256] = 0;
    __syncthreads();
    const bool useStage = (m <= STAGE_CAP);
    for (int i = t; i < m; i += 256) {
        unsigned p = pairbuf[pBeg + i];
        if (useStage) stage[i] = p;
        atomicAdd(&cnt[p >> 17], 1);
    }
    __syncthreads();
    const int c0 = cnt[2 * t], c1 = cnt[2 * t + 1];
    const int pairSum = c0 + c1;
    sb[t] = pairSum;
    __syncthreads();
    for (int off = 1; off < 256; off <<= 1) {
        int u = (t >= off) ? sb[t - off] : 0;
        __syncthreads();
        sb[t] += u;
        __syncthreads();
    }
    const int excl = sb[t] - pairSum;
    rb[2 * t] = excl;
    rb[2 * t + 1] = excl + c0;
    __syncthreads();
    const int nodeBase = b << BBITS;
    for (int local = t; local < BSIZE; local += 256) {
        int node = nodeBase + local;
        if (node < n) {
            int beg = pBeg + rb[local];
            rowbeg[node] = beg;
            rowend[node] = beg + cnt[local];
            dinv[node] = rsqrtf((float)(cnt[local] + 1));  // +1 self-loop
        }
    }
    for (int i = t; i < m; i += 256) {
        unsigned p = useStage ? stage[i] : pairbuf[pBeg + i];
        int local = (int)(p >> 17);
        int s = (int)(p & 0x1FFFF);
        int pos = pBeg + rb[local] + atomicAdd(&cur[local], 1);
        adj[pos] = s;
    }
}

// MFMA GEMM (layer 0 only): T'[n x 64] (fp16) = (x[n x 128] fp32 @ W0) * dinv.
__global__ __launch_bounds__(256) void gemm0_kernel(const float* __restrict__ X, const __half* __restrict__ Wt,
                                                    const float* __restrict__ dinv, __half* __restrict__ T, int n) {
    constexpr int K = 128;
    __shared__ __half sOut[4][16][72];
    const int tid = threadIdx.x;
    const int w = tid >> 6;
    const int l = tid & 63;
    const int l15 = l & 15;
    const int kg = l >> 4;
    const int rowBase = blockIdx.x * 64 + w * 16;

    f32x4 acc0 = {0.f, 0.f, 0.f, 0.f};
    f32x4 acc1 = acc0, acc2 = acc0, acc3 = acc0;
    const int m = rowBase + l15;
    const int mc = (m < n) ? m : (n - 1);

    for (int kc = 0; kc < K / 32; ++kc) {
        const int kb = kc * 32 + kg * 8;
        const float* Xp = X + (long)mc * K + kb;
        const float4 f0 = *reinterpret_cast<const float4*>(Xp);
        const float4 f1 = *reinterpret_cast<const float4*>(Xp + 4);
        half8 a;
        a[0] = (_Float16)f0.x; a[1] = (_Float16)f0.y; a[2] = (_Float16)f0.z; a[3] = (_Float16)f0.w;
        a[4] = (_Float16)f1.x; a[5] = (_Float16)f1.y; a[6] = (_Float16)f1.z; a[7] = (_Float16)f1.w;
        const half8 b0 = *reinterpret_cast<const half8*>(Wt + (long)(0 * 16 + l15) * K + kb);
        const half8 b1 = *reinterpret_cast<const half8*>(Wt + (long)(1 * 16 + l15) * K + kb);
        const half8 b2 = *reinterpret_cast<const half8*>(Wt + (long)(2 * 16 + l15) * K + kb);
        const half8 b3 = *reinterpret_cast<const half8*>(Wt + (long)(3 * 16 + l15) * K + kb);
        acc0 = __builtin_amdgcn_mfma_f32_16x16x32_f16(a, b0, acc0, 0, 0, 0);
        acc1 = __builtin_amdgcn_mfma_f32_16x16x32_f16(a, b1, acc1, 0, 0, 0);
        acc2 = __builtin_amdgcn_mfma_f32_16x16x32_f16(a, b2, acc2, 0, 0, 0);
        acc3 = __builtin_amdgcn_mfma_f32_16x16x32_f16(a, b3, acc3, 0, 0, 0);
    }

    float di[4];
    #pragma unroll
    for (int r = 0; r < 4; ++r) {
        const int mr = rowBase + kg * 4 + r;
        di[r] = dinv[(mr < n) ? mr : (n - 1)];
    }
    #pragma unroll
    for (int r = 0; r < 4; ++r) {
        sOut[w][kg * 4 + r][0 * 16 + l15] = (__half)(acc0[r] * di[r]);
        sOut[w][kg * 4 + r][1 * 16 + l15] = (__half)(acc1[r] * di[r]);
        sOut[w][kg * 4 + r][2 * 16 + l15] = (__half)(acc2[r] * di[r]);
        sOut[w][kg * 4 + r][3 * 16 + l15] = (__half)(acc3[r] * di[r]);
    }
    __syncthreads();
    const int srow = l >> 2;
    const int scol = (l & 3) * 16;
    const int gm = rowBase + srow;
    if (gm < n) {
        const uint4 q0 = *reinterpret_cast<const uint4*>(&sOut[w][srow][scol]);
        const uint4 q1 = *reinterpret_cast<const uint4*>(&sOut[w][srow][scol + 8]);
        *reinterpret_cast<uint4*>(&T[(long)gm * 64 + scol]) = q0;
        *reinterpret_cast<uint4*>(&T[(long)gm * 64 + scol + 8]) = q1;
    }
}

__device__ __forceinline__ void accum_row(const uint4& r, __half2& x0, __half2& x1, __half2& x2, __half2& x3) {
    const __half2* v = reinterpret_cast<const __half2*>(&r);
    x0 = __hadd2(x0, v[0]); x1 = __hadd2(x1, v[1]);
    x2 = __hadd2(x2, v[2]); x3 = __hadd2(x3, v[3]);
}

// FUSED agg + MFMA gemm. Gather h_l per node (8-lane subgroup, batched-8,
// leaky) -> LDS [32][72] -> per-wave MFMA (16 nodes x 16-col groups) with
// B-frags from Wt (next layer) -> dinv-scale -> LDS transpose -> T'_{l+1}.
// OUTC = 64 or 48 (48: cols >= 40 are zero-padded W; store 40).
template<int OUTC>
__global__ __launch_bounds__(256) void agg_gemm_kernel(const __half* __restrict__ Tp, const float* __restrict__ dinv,
                                                       const int* __restrict__ rowbeg, const int* __restrict__ rowend,
                                                       const int* __restrict__ adj, const float* __restrict__ bias,
                                                       const __half* __restrict__ Wt, __half* __restrict__ Tout, int n) {
    __shared__ __half hl[32][72];
    const int tid = threadIdx.x;
    const int c = tid & 7;
    const int dl = tid >> 3;                  // local node 0..31
    const int blockbase = blockIdx.x * 32;
    int d = blockbase + dl;
    const bool dok = (d < n);
    if (!dok) d = n - 1;
    const uint4* Tp4 = reinterpret_cast<const uint4*>(Tp);

    // ---- gather phase (input always 64 cols, CHS=8) ----
    __half2 a0 = __float2half2_rn(0.f), a1 = a0, a2 = a0, a3 = a0;
    __half2 c0 = a0, c1 = a0, c2 = a0, c3 = a0;
    const int beg = rowbeg[d], end = rowend[d];
    int e0 = beg;
    for (; e0 + 8 <= end; e0 += 8) {
        const int myadj = adj[e0 + c];
        uint4 r[8];
        #pragma unroll
        for (int j = 0; j < 8; ++j) {
            const int s = __shfl(myadj, j, 8);
            r[j] = Tp4[(long)s * 8 + c];
        }
        accum_row(r[0], a0, a1, a2, a3);
        accum_row(r[1], c0, c1, c2, c3);
        accum_row(r[2], a0, a1, a2, a3);
        accum_row(r[3], c0, c1, c2, c3);
        accum_row(r[4], a0, a1, a2, a3);
        accum_row(r[5], c0, c1, c2, c3);
        accum_row(r[6], a0, a1, a2, a3);
        accum_row(r[7], c0, c1, c2, c3);
    }
    if (e0 < end) {
        const int last = end - 1;
        const int idx = e0 + c;
        const int myadj = adj[idx <= last ? idx : last];
        uint4 r[8];
        #pragma unroll
        for (int j = 0; j < 8; ++j) {
            const int s = __shfl(myadj, j, 8);
            r[j] = Tp4[(long)s * 8 + c];
        }
        #pragma unroll
        for (int j = 0; j < 8; ++j) {
            if (e0 + j <= last) {
                if (j & 1) accum_row(r[j], c0, c1, c2, c3);
                else       accum_row(r[j], a0, a1, a2, a3);
            }
        }
    }
    {
        const uint4 sraw = Tp4[(long)d * 8 + c];          // self-loop
        const __half2* sh = reinterpret_cast<const __half2*>(&sraw);
        a0 = __hadd2(__hadd2(a0, c0), sh[0]);
        a1 = __hadd2(__hadd2(a1, c1), sh[1]);
        a2 = __hadd2(__hadd2(a2, c2), sh[2]);
        a3 = __hadd2(__hadd2(a3, c3), sh[3]);
        const float di = dinv[d];
        const float4 b0 = *reinterpret_cast<const float4*>(&bias[c * 8]);
        const float4 b1 = *reinterpret_cast<const float4*>(&bias[c * 8 + 4]);
        const float2 f0 = __half22float2(a0), f1 = __half22float2(a1);
        const float2 f2 = __half22float2(a2), f3 = __half22float2(a3);
        float vals[8];
        vals[0] = f0.x * di + b0.x; vals[1] = f0.y * di + b0.y;
        vals[2] = f1.x * di + b0.z; vals[3] = f1.y * di + b0.w;
        vals[4] = f2.x * di + b1.x; vals[5] = f2.y * di + b1.y;
        vals[6] = f3.x * di + b1.z; vals[7] = f3.y * di + b1.w;
        union { __half h[8]; uint4 u; } ph;
        #pragma unroll
        for (int j = 0; j < 8; ++j) {
            const float v = vals[j];
            ph.h[j] = (__half)(v > 0.f ? v : 0.01f * v);   // leaky
        }
        *reinterpret_cast<uint4*>(&hl[dl][c * 8]) = ph.u;
    }
    __syncthreads();

    // ---- MFMA phase: wave w -> nodes (w>>1)*16..+16, cols (w&1)*32..  ----
    const int w = tid >> 6;
    const int l = tid & 63;
    const int l15 = l & 15;
    const int kg = l >> 4;
    const int ng = (w >> 1) * 16;
    const int colbase = (w & 1) * 32;
    const int ncg = (OUTC == 64) ? 2 : ((w & 1) ? 1 : 2);   // OUTC=48: cols 0-31 + 32-47

    const half8 af0 = *reinterpret_cast<const half8*>(&hl[ng + l15][0 * 32 + kg * 8]);
    const half8 af1 = *reinterpret_cast<const half8*>(&hl[ng + l15][1 * 32 + kg * 8]);
    half8 bf[2][2];
    #pragma unroll
    for (int cg = 0; cg < 2; ++cg) {
        if (cg < ncg) {
            #pragma unroll
            for (int kc = 0; kc < 2; ++kc)
                bf[cg][kc] = *reinterpret_cast<const half8*>(&Wt[(long)(colbase + cg * 16 + l15) * 64 + kc * 32 + kg * 8]);
        }
    }
    __syncthreads();   // all hl reads done before D writes

    f32x4 dacc[2];
    dacc[0] = (f32x4){0.f, 0.f, 0.f, 0.f};
    dacc[1] = (f32x4){0.f, 0.f, 0.f, 0.f};
    #pragma unroll
    for (int cg = 0; cg < 2; ++cg) {
        if (cg < ncg) {
            dacc[cg] = __builtin_amdgcn_mfma_f32_16x16x32_f16(af0, bf[cg][0], dacc[cg], 0, 0, 0);
            dacc[cg] = __builtin_amdgcn_mfma_f32_16x16x32_f16(af1, bf[cg][1], dacc[cg], 0, 0, 0);
        }
    }

    // dinv-scale rows (node = blockbase + ng + kg*4 + r) and write D to LDS.
    float di[4];
    #pragma unroll
    for (int r = 0; r < 4; ++r) {
        const int nd = blockbase + ng + kg * 4 + r;
        di[r] = dinv[(nd < n) ? nd : (n - 1)];
    }
    #pragma unroll
    for (int cg = 0; cg < 2; ++cg) {
        if (cg < ncg) {
            #pragma unroll
            for (int r = 0; r < 4; ++r)
                hl[ng + kg * 4 + r][colbase + cg * 16 + l15] = (__half)(dacc[cg][r] * di[r]);
        }
    }
    __syncthreads();

    // ---- coalesced store ----
    if constexpr (OUTC == 64) {
        const int r = tid >> 3, ch = tid & 7;
        if (blockbase + r < n)
            *reinterpret_cast<uint4*>(&Tout[(long)(blockbase + r) * 64 + ch * 8]) =
                *reinterpret_cast<const uint4*>(&hl[r][ch * 8]);
    } else {  // store 40 of 48 cols
        if (tid < 160) {
            const int r = tid / 5, ch = tid - 5 * r;
            if (blockbase + r < n)
                *reinterpret_cast<uint4*>(&Tout[(long)(blockbase + r) * 40 + ch * 8]) =
                    *reinterpret_cast<const uint4*>(&hl[r][ch * 8]);
        }
    }
}

// Final agg + softmax (input T3 [n][40] fp16).
__global__ __launch_bounds__(256) void agg_sm_kernel(const __half* __restrict__ Tp, const float* __restrict__ dinv,
                                                     const int* __restrict__ rowbeg, const int* __restrict__ rowend,
                                                     const int* __restrict__ adj,
                                                     const float* __restrict__ bias, float* __restrict__ out, int n) {
    constexpr int CHS = 5;
    const int tid = threadIdx.x;
    const int c = tid & 7;
    const int d = (int)((blockIdx.x * 256 + tid) >> 3);
    if (d >= n) return;
    const bool act = (c < CHS);
    const int cc = act ? c : (CHS - 1);
    const uint4* Tp4 = reinterpret_cast<const uint4*>(Tp);

    __half2 a0 = __float2half2_rn(0.f), a1 = a0, a2 = a0, a3 = a0;
    __half2 c0 = a0, c1 = a0, c2 = a0, c3 = a0;
    const int beg = rowbeg[d], end = rowend[d];
    int e0 = beg;
    for (; e0 + 8 <= end; e0 += 8) {
        const int myadj = adj[e0 + c];
        uint4 r[8];
        #pragma unroll
        for (int j = 0; j < 8; ++j) {
            const int s = __shfl(myadj, j, 8);
            r[j] = Tp4[(long)s * CHS + cc];
        }
        accum_row(r[0], a0, a1, a2, a3);
        accum_row(r[1], c0, c1, c2, c3);
        accum_row(r[2], a0, a1, a2, a3);
        accum_row(r[3], c0, c1, c2, c3);
        accum_row(r[4], a0, a1, a2, a3);
        accum_row(r[5], c0, c1, c2, c3);
        accum_row(r[6], a0, a1, a2, a3);
        accum_row(r[7], c0, c1, c2, c3);
    }
    if (e0 < end) {
        const int last = end - 1;
        const int idx = e0 + c;
        const int myadj = adj[idx <= last ? idx : last];
        uint4 r[8];
        #pragma unroll
        for (int j = 0; j < 8; ++j) {
            const int s = __shfl(myadj, j, 8);
            r[j] = Tp4[(long)s * CHS + cc];
        }
        #pragma unroll
        for (int j = 0; j < 8; ++j) {
            if (e0 + j <= last) {
                if (j & 1) accum_row(r[j], c0, c1, c2, c3);
                else       accum_row(r[j], a0, a1, a2, a3);
            }
        }
    }

    float vals[8];
    if (act) {
        const uint4 sraw = Tp4[(long)d * CHS + c];
        const __half2* sh = reinterpret_cast<const __half2*>(&sraw);
        a0 = __hadd2(__hadd2(a0, c0), sh[0]);
        a1 = __hadd2(__hadd2(a1, c1), sh[1]);
        a2 = __hadd2(__hadd2(a2, c2), sh[2]);
        a3 = __hadd2(__hadd2(a3, c3), sh[3]);
        const float di = dinv[d];
        const float4 b0 = *reinterpret_cast<const float4*>(&bias[c * 8]);
        const float4 b1 = *reinterpret_cast<const float4*>(&bias[c * 8 + 4]);
        const float2 f0 = __half22float2(a0), f1 = __half22float2(a1);
        const float2 f2 = __half22float2(a2), f3 = __half22float2(a3);
        vals[0] = f0.x * di + b0.x; vals[1] = f0.y * di + b0.y;
        vals[2] = f1.x * di + b0.z; vals[3] = f1.y * di + b0.w;
        vals[4] = f2.x * di + b1.x; vals[5] = f2.y * di + b1.y;
        vals[6] = f3.x * di + b1.z; vals[7] = f3.y * di + b1.w;
    }
    float mx = -1e30f;
    if (act) {
        #pragma unroll
        for (int j = 0; j < 8; ++j) mx = fmaxf(mx, vals[j]);
    }
    #pragma unroll
    for (int off = 1; off <= 4; off <<= 1) mx = fmaxf(mx, __shfl_xor(mx, off, 8));
    float e8[8];
    float sum = 0.f;
    if (act) {
        #pragma unroll
        for (int j = 0; j < 8; ++j) { e8[j] = expf(vals[j] - mx); sum += e8[j]; }
    }
    #pragma unroll
    for (int off = 1; off <= 4; off <<= 1) sum += __shfl_xor(sum, off, 8);
    if (act) {
        const float inv = 1.0f / sum;
        const float4 o0 = make_float4(e8[0] * inv, e8[1] * inv, e8[2] * inv, e8[3] * inv);
        const float4 o1 = make_float4(e8[4] * inv, e8[5] * inv, e8[6] * inv, e8[7] * inv);
        *reinterpret_cast<float4*>(&out[(long)d * 40 + c * 8]) = o0;
        *reinterpret_cast<float4*>(&out[(long)d * 40 + c * 8 + 4]) = o1;
    }
}

extern "C" void kernel_launch(void* const* d_in, const int* in_sizes, int n_in,
                              void* d_out, int out_size, void* d_ws, size_t ws_size,
                              hipStream_t stream) {
    const float* x  = (const float*)d_in[0];
    const int*   ei = (const int*)d_in[1];
    const float* W0 = (const float*)d_in[2];
    const float* b0 = (const float*)d_in[3];
    const float* W1 = (const float*)d_in[4];
    const float* b1 = (const float*)d_in[5];
    const float* W2 = (const float*)d_in[6];
    const float* b2 = (const float*)d_in[7];
    const float* W3 = (const float*)d_in[8];
    const float* b3 = (const float*)d_in[9];

    const int N = in_sizes[0] / 128;
    const int E = in_sizes[1] / 2;
    const int* src = ei;
    const int* dst = ei + E;

    const int nBuck = (N + BSIZE - 1) >> BBITS;   // 196

    char* ws = (char*)d_ws;
    auto align256 = [](size_t v) { return (v + 255) & ~(size_t)255; };
    size_t o = 0;
    int*    gCursor    = (int*)(ws + o);    o += align256(256 * 4);
    int*    rowbeg     = (int*)(ws + o);    o += align256((size_t)N * 4);
    int*    rowend     = (int*)(ws + o);    o += align256((size_t)N * 4);
    float*  dinv       = (float*)(ws + o);  o += align256((size_t)N * 4);
    int*    adj        = (int*)(ws + o);    o += align256((size_t)nBuck * BCAP * 4);
    __half* Wt0        = (__half*)(ws + o); o += align256(64 * 128 * 2);
    __half* Wt1        = (__half*)(ws + o); o += align256(64 * 64 * 2);
    __half* Wt2        = (__half*)(ws + o); o += align256(64 * 64 * 2);
    __half* Wt3        = (__half*)(ws + o); o += align256(48 * 64 * 2);
    __half* T          = (__half*)(ws + o); o += align256((size_t)N * 64 * 2);
    __half* B          = (__half*)(ws + o); o += align256((size_t)N * 64 * 2);
    unsigned* pairbuf  = (unsigned*)T;      // alias: 8.0 MB <= 12.8 MB; consumed before gemm0 writes T
    float* OUT         = (float*)d_out;

    const int nb_gemm0 = (N + 63) / 64;
    const int nb_fused = (N + 31) / 32;
    const int nb_aggsm = (N * 8 + 255) / 256;
    const int nb_passA = (E + CHUNK - 1) / CHUNK;

    // Build CSR + dinv + fp16 weights (memset + 2 dispatches)
    hipMemsetAsync(gCursor, 0, 1024, stream);
    passA_kernel<<<nb_passA + 4, 256, 0, stream>>>(src, dst, gCursor, pairbuf, E, nb_passA,
                                                   W0, W1, W2, W3, Wt0, Wt1, Wt2, Wt3);
    passB_kernel<<<nBuck, 256, 0, stream>>>(pairbuf, gCursor, rowbeg, rowend, dinv, adj, N);

    // Layer 0 GEMM: x -> T (= T'_1)
    gemm0_kernel<<<nb_gemm0, 256, 0, stream>>>(x, Wt0, dinv, T, N);
    // Fused layers: agg + leaky + gemm_{l+1}
    agg_gemm_kernel<64><<<nb_fused, 256, 0, stream>>>(T, dinv, rowbeg, rowend, adj, b0, Wt1, B, N);  // -> T'_2
    agg_gemm_kernel<64><<<nb_fused, 256, 0, stream>>>(B, dinv, rowbeg, rowend, adj, b1, Wt2, T, N);  // -> T'_3
    agg_gemm_kernel<48><<<nb_fused, 256, 0, stream>>>(T, dinv, rowbeg, rowend, adj, b2, Wt3, B, N);  // -> T3 [N][40]
    // Final agg + softmax
    agg_sm_kernel<<<nb_aggsm, 256, 0, stream>>>(B, dinv, rowbeg, rowend, adj, b3, OUT, N);
}

// Round 18
// 207.061 us; speedup vs baseline: 1.0600x; 1.0600x over previous
//
#include <hip/hip_runtime.h>
#include <hip/hip_fp16.h>
#include <math.h>

// GCN: CSR via single-pass bucket scatter; gemm0 (MFMA); then 3 FUSED
// agg+MFMA-gemm kernels (gather h in-register -> LDS -> MFMA with next layer's
// W -> T'_{l+1} directly); final agg+softmax. T' fp16.
// out[d] = dinv[d]*(T'[d] + sum_{s in N(d)} T'[s]) + b, T'[i] = dinv[i]*(h[i]@W).
// R17 = R15 exact (best verified config, 207.7 us): CHUNK=2048 passA with
// global re-read (R16's CHUNK=1024 + reg-held edges regressed: 2x per-block
// fixed cost + shorter scatter runs).

#define BBITS 9
#define BSIZE 512
#define BCAP 10240
#define CHUNK 2048
#define STAGE_CAP 12288

typedef __attribute__((ext_vector_type(8))) _Float16 half8;
typedef __attribute__((ext_vector_type(4))) float f32x4;

// Bucket-scatter into region b*BCAP (plain stores; nontemporal caused 3.4x
// write amplification in R14). Blocks >= nPassA transpose weights to fp16.
__global__ __launch_bounds__(256) void passA_kernel(const int* __restrict__ src, const int* __restrict__ dst,
                                                    int* gCursor, unsigned* __restrict__ pairbuf,
                                                    int nE, int nPassA,
                                                    const float* __restrict__ W0, const float* __restrict__ W1,
                                                    const float* __restrict__ W2, const float* __restrict__ W3,
                                                    __half* __restrict__ Wt0, __half* __restrict__ Wt1,
                                                    __half* __restrict__ Wt2, __half* __restrict__ Wt3) {
    const int t = threadIdx.x;
    if (blockIdx.x >= nPassA) {
        const int b = blockIdx.x - nPassA;   // 0..3
        if (b < 3) {
            const float* W = (b == 0) ? W0 : (b == 1) ? W1 : W2;
            __half* Wt = (b == 0) ? Wt0 : (b == 1) ? Wt1 : Wt2;
            const int K = (b == 0) ? 128 : 64;
            const int tot = 64 * K;
            for (int i = t; i < tot; i += 256) {
                int nn = i / K, k = i - nn * K;
                Wt[i] = (__half)W[k * 64 + nn];
            }
        } else {
            for (int i = t; i < 48 * 64; i += 256) {      // Wt3 [48][64], cols>=40 zero
                int c = i >> 6, k = i & 63;
                Wt3[i] = (c < 40) ? (__half)W3[k * 40 + c] : (__half)0.f;
            }
        }
        return;
    }
    __shared__ int hist[256], base[256], offs[256];
    hist[t] = 0; offs[t] = 0;
    __syncthreads();
    const int e0 = blockIdx.x * CHUNK;
    #pragma unroll
    for (int i = 0; i < CHUNK / 256; ++i) {
        int e = e0 + i * 256 + t;
        if (e < nE) atomicAdd(&hist[dst[e] >> BBITS], 1);
    }
    __syncthreads();
    if (hist[t]) base[t] = atomicAdd(&gCursor[t], hist[t]);
    __syncthreads();
    #pragma unroll
    for (int i = 0; i < CHUNK / 256; ++i) {
        int e = e0 + i * 256 + t;
        if (e < nE) {
            int d = dst[e];
            int b = d >> BBITS;
            int pos = b * BCAP + base[b] + atomicAdd(&offs[b], 1);
            pairbuf[pos] = (unsigned)src[e] | ((unsigned)(d & (BSIZE - 1)) << 17);
        }
    }
}

// Per-bucket: stage pairs, LDS count, scan, write rowbeg/rowend/dinv, place adj.
__global__ __launch_bounds__(256) void passB_kernel(const unsigned* __restrict__ pairbuf, const int* __restrict__ gCursor,
                                                    int* __restrict__ rowbeg, int* __restrict__ rowend,
                                                    float* __restrict__ dinv, int* __restrict__ adj, int n) {
    __shared__ unsigned stage[STAGE_CAP];
    __shared__ int cnt[BSIZE], rb[BSIZE], cur[BSIZE];
    __shared__ int sb[256];
    const int t = threadIdx.x;
    const int b = blockIdx.x;
    const int pBeg = b * BCAP;
    const int m = gCursor[b];
    cnt[t] = 0; cnt[t + 256] = 0; cur[t] = 0; cur[t + 256] = 0;
    __syncthreads();
    const bool useStage = (m <= STAGE_CAP);
    for (int i = t; i < m; i += 256) {
        unsigned p = pairbuf[pBeg + i];
        if (useStage) stage[i] = p;
        atomicAdd(&cnt[p >> 17], 1);
    }
    __syncthreads();
    const int c0 = cnt[2 * t], c1 = cnt[2 * t + 1];
    const int pairSum = c0 + c1;
    sb[t] = pairSum;
    __syncthreads();
    for (int off = 1; off < 256; off <<= 1) {
        int u = (t >= off) ? sb[t - off] : 0;
        __syncthreads();
        sb[t] += u;
        __syncthreads();
    }
    const int excl = sb[t] - pairSum;
    rb[2 * t] = excl;
    rb[2 * t + 1] = excl + c0;
    __syncthreads();
    const int nodeBase = b << BBITS;
    for (int local = t; local < BSIZE; local += 256) {
        int node = nodeBase + local;
        if (node < n) {
            int beg = pBeg + rb[local];
            rowbeg[node] = beg;
            rowend[node] = beg + cnt[local];
            dinv[node] = rsqrtf((float)(cnt[local] + 1));  // +1 self-loop
        }
    }
    for (int i = t; i < m; i += 256) {
        unsigned p = useStage ? stage[i] : pairbuf[pBeg + i];
        int local = (int)(p >> 17);
        int s = (int)(p & 0x1FFFF);
        int pos = pBeg + rb[local] + atomicAdd(&cur[local], 1);
        adj[pos] = s;
    }
}

// MFMA GEMM (layer 0 only): T'[n x 64] (fp16) = (x[n x 128] fp32 @ W0) * dinv.
__global__ __launch_bounds__(256) void gemm0_kernel(const float* __restrict__ X, const __half* __restrict__ Wt,
                                                    const float* __restrict__ dinv, __half* __restrict__ T, int n) {
    constexpr int K = 128;
    __shared__ __half sOut[4][16][72];
    const int tid = threadIdx.x;
    const int w = tid >> 6;
    const int l = tid & 63;
    const int l15 = l & 15;
    const int kg = l >> 4;
    const int rowBase = blockIdx.x * 64 + w * 16;

    f32x4 acc0 = {0.f, 0.f, 0.f, 0.f};
    f32x4 acc1 = acc0, acc2 = acc0, acc3 = acc0;
    const int m = rowBase + l15;
    const int mc = (m < n) ? m : (n - 1);

    for (int kc = 0; kc < K / 32; ++kc) {
        const int kb = kc * 32 + kg * 8;
        const float* Xp = X + (long)mc * K + kb;
        const float4 f0 = *reinterpret_cast<const float4*>(Xp);
        const float4 f1 = *reinterpret_cast<const float4*>(Xp + 4);
        half8 a;
        a[0] = (_Float16)f0.x; a[1] = (_Float16)f0.y; a[2] = (_Float16)f0.z; a[3] = (_Float16)f0.w;
        a[4] = (_Float16)f1.x; a[5] = (_Float16)f1.y; a[6] = (_Float16)f1.z; a[7] = (_Float16)f1.w;
        const half8 b0 = *reinterpret_cast<const half8*>(Wt + (long)(0 * 16 + l15) * K + kb);
        const half8 b1 = *reinterpret_cast<const half8*>(Wt + (long)(1 * 16 + l15) * K + kb);
        const half8 b2 = *reinterpret_cast<const half8*>(Wt + (long)(2 * 16 + l15) * K + kb);
        const half8 b3 = *reinterpret_cast<const half8*>(Wt + (long)(3 * 16 + l15) * K + kb);
        acc0 = __builtin_amdgcn_mfma_f32_16x16x32_f16(a, b0, acc0, 0, 0, 0);
        acc1 = __builtin_amdgcn_mfma_f32_16x16x32_f16(a, b1, acc1, 0, 0, 0);
        acc2 = __builtin_amdgcn_mfma_f32_16x16x32_f16(a, b2, acc2, 0, 0, 0);
        acc3 = __builtin_amdgcn_mfma_f32_16x16x32_f16(a, b3, acc3, 0, 0, 0);
    }

    float di[4];
    #pragma unroll
    for (int r = 0; r < 4; ++r) {
        const int mr = rowBase + kg * 4 + r;
        di[r] = dinv[(mr < n) ? mr : (n - 1)];
    }
    #pragma unroll
    for (int r = 0; r < 4; ++r) {
        sOut[w][kg * 4 + r][0 * 16 + l15] = (__half)(acc0[r] * di[r]);
        sOut[w][kg * 4 + r][1 * 16 + l15] = (__half)(acc1[r] * di[r]);
        sOut[w][kg * 4 + r][2 * 16 + l15] = (__half)(acc2[r] * di[r]);
        sOut[w][kg * 4 + r][3 * 16 + l15] = (__half)(acc3[r] * di[r]);
    }
    __syncthreads();
    const int srow = l >> 2;
    const int scol = (l & 3) * 16;
    const int gm = rowBase + srow;
    if (gm < n) {
        const uint4 q0 = *reinterpret_cast<const uint4*>(&sOut[w][srow][scol]);
        const uint4 q1 = *reinterpret_cast<const uint4*>(&sOut[w][srow][scol + 8]);
        *reinterpret_cast<uint4*>(&T[(long)gm * 64 + scol]) = q0;
        *reinterpret_cast<uint4*>(&T[(long)gm * 64 + scol + 8]) = q1;
    }
}

__device__ __forceinline__ void accum_row(const uint4& r, __half2& x0, __half2& x1, __half2& x2, __half2& x3) {
    const __half2* v = reinterpret_cast<const __half2*>(&r);
    x0 = __hadd2(x0, v[0]); x1 = __hadd2(x1, v[1]);
    x2 = __hadd2(x2, v[2]); x3 = __hadd2(x3, v[3]);
}

// FUSED agg + MFMA gemm. Gather h_l per node (8-lane subgroup, batched-8,
// leaky) -> LDS [32][72] -> per-wave MFMA (16 nodes x 16-col groups) with
// B-frags from Wt (next layer) -> dinv-scale -> LDS transpose -> T'_{l+1}.
// OUTC = 64 or 48 (48: cols >= 40 are zero-padded W; store 40).
template<int OUTC>
__global__ __launch_bounds__(256) void agg_gemm_kernel(const __half* __restrict__ Tp, const float* __restrict__ dinv,
                                                       const int* __restrict__ rowbeg, const int* __restrict__ rowend,
                                                       const int* __restrict__ adj, const float* __restrict__ bias,
                                                       const __half* __restrict__ Wt, __half* __restrict__ Tout, int n) {
    __shared__ __half hl[32][72];
    const int tid = threadIdx.x;
    const int c = tid & 7;
    const int dl = tid >> 3;                  // local node 0..31
    const int blockbase = blockIdx.x * 32;
    int d = blockbase + dl;
    const bool dok = (d < n);
    if (!dok) d = n - 1;
    const uint4* Tp4 = reinterpret_cast<const uint4*>(Tp);

    // ---- gather phase (input always 64 cols, CHS=8) ----
    __half2 a0 = __float2half2_rn(0.f), a1 = a0, a2 = a0, a3 = a0;
    __half2 c0 = a0, c1 = a0, c2 = a0, c3 = a0;
    const int beg = rowbeg[d], end = rowend[d];
    int e0 = beg;
    for (; e0 + 8 <= end; e0 += 8) {
        const int myadj = adj[e0 + c];
        uint4 r[8];
        #pragma unroll
        for (int j = 0; j < 8; ++j) {
            const int s = __shfl(myadj, j, 8);
            r[j] = Tp4[(long)s * 8 + c];
        }
        accum_row(r[0], a0, a1, a2, a3);
        accum_row(r[1], c0, c1, c2, c3);
        accum_row(r[2], a0, a1, a2, a3);
        accum_row(r[3], c0, c1, c2, c3);
        accum_row(r[4], a0, a1, a2, a3);
        accum_row(r[5], c0, c1, c2, c3);
        accum_row(r[6], a0, a1, a2, a3);
        accum_row(r[7], c0, c1, c2, c3);
    }
    if (e0 < end) {
        const int last = end - 1;
        const int idx = e0 + c;
        const int myadj = adj[idx <= last ? idx : last];
        uint4 r[8];
        #pragma unroll
        for (int j = 0; j < 8; ++j) {
            const int s = __shfl(myadj, j, 8);
            r[j] = Tp4[(long)s * 8 + c];
        }
        #pragma unroll
        for (int j = 0; j < 8; ++j) {
            if (e0 + j <= last) {
                if (j & 1) accum_row(r[j], c0, c1, c2, c3);
                else       accum_row(r[j], a0, a1, a2, a3);
            }
        }
    }
    {
        const uint4 sraw = Tp4[(long)d * 8 + c];          // self-loop
        const __half2* sh = reinterpret_cast<const __half2*>(&sraw);
        a0 = __hadd2(__hadd2(a0, c0), sh[0]);
        a1 = __hadd2(__hadd2(a1, c1), sh[1]);
        a2 = __hadd2(__hadd2(a2, c2), sh[2]);
        a3 = __hadd2(__hadd2(a3, c3), sh[3]);
        const float di = dinv[d];
        const float4 b0 = *reinterpret_cast<const float4*>(&bias[c * 8]);
        const float4 b1 = *reinterpret_cast<const float4*>(&bias[c * 8 + 4]);
        const float2 f0 = __half22float2(a0), f1 = __half22float2(a1);
        const float2 f2 = __half22float2(a2), f3 = __half22float2(a3);
        float vals[8];
        vals[0] = f0.x * di + b0.x; vals[1] = f0.y * di + b0.y;
        vals[2] = f1.x * di + b0.z; vals[3] = f1.y * di + b0.w;
        vals[4] = f2.x * di + b1.x; vals[5] = f2.y * di + b1.y;
        vals[6] = f3.x * di + b1.z; vals[7] = f3.y * di + b1.w;
        union { __half h[8]; uint4 u; } ph;
        #pragma unroll
        for (int j = 0; j < 8; ++j) {
            const float v = vals[j];
            ph.h[j] = (__half)(v > 0.f ? v : 0.01f * v);   // leaky
        }
        *reinterpret_cast<uint4*>(&hl[dl][c * 8]) = ph.u;
    }
    __syncthreads();

    // ---- MFMA phase: wave w -> nodes (w>>1)*16..+16, cols (w&1)*32..  ----
    const int w = tid >> 6;
    const int l = tid & 63;
    const int l15 = l & 15;
    const int kg = l >> 4;
    const int ng = (w >> 1) * 16;
    const int colbase = (w & 1) * 32;
    const int ncg = (OUTC == 64) ? 2 : ((w & 1) ? 1 : 2);   // OUTC=48: cols 0-31 + 32-47

    const half8 af0 = *reinterpret_cast<const half8*>(&hl[ng + l15][0 * 32 + kg * 8]);
    const half8 af1 = *reinterpret_cast<const half8*>(&hl[ng + l15][1 * 32 + kg * 8]);
    half8 bf[2][2];
    #pragma unroll
    for (int cg = 0; cg < 2; ++cg) {
        if (cg < ncg) {
            #pragma unroll
            for (int kc = 0; kc < 2; ++kc)
                bf[cg][kc] = *reinterpret_cast<const half8*>(&Wt[(long)(colbase + cg * 16 + l15) * 64 + kc * 32 + kg * 8]);
        }
    }
    __syncthreads();   // all hl reads done before D writes

    f32x4 dacc[2];
    dacc[0] = (f32x4){0.f, 0.f, 0.f, 0.f};
    dacc[1] = (f32x4){0.f, 0.f, 0.f, 0.f};
    #pragma unroll
    for (int cg = 0; cg < 2; ++cg) {
        if (cg < ncg) {
            dacc[cg] = __builtin_amdgcn_mfma_f32_16x16x32_f16(af0, bf[cg][0], dacc[cg], 0, 0, 0);
            dacc[cg] = __builtin_amdgcn_mfma_f32_16x16x32_f16(af1, bf[cg][1], dacc[cg], 0, 0, 0);
        }
    }

    // dinv-scale rows (node = blockbase + ng + kg*4 + r) and write D to LDS.
    float di[4];
    #pragma unroll
    for (int r = 0; r < 4; ++r) {
        const int nd = blockbase + ng + kg * 4 + r;
        di[r] = dinv[(nd < n) ? nd : (n - 1)];
    }
    #pragma unroll
    for (int cg = 0; cg < 2; ++cg) {
        if (cg < ncg) {
            #pragma unroll
            for (int r = 0; r < 4; ++r)
                hl[ng + kg * 4 + r][colbase + cg * 16 + l15] = (__half)(dacc[cg][r] * di[r]);
        }
    }
    __syncthreads();

    // ---- coalesced store ----
    if constexpr (OUTC == 64) {
        const int r = tid >> 3, ch = tid & 7;
        if (blockbase + r < n)
            *reinterpret_cast<uint4*>(&Tout[(long)(blockbase + r) * 64 + ch * 8]) =
                *reinterpret_cast<const uint4*>(&hl[r][ch * 8]);
    } else {  // store 40 of 48 cols
        if (tid < 160) {
            const int r = tid / 5, ch = tid - 5 * r;
            if (blockbase + r < n)
                *reinterpret_cast<uint4*>(&Tout[(long)(blockbase + r) * 40 + ch * 8]) =
                    *reinterpret_cast<const uint4*>(&hl[r][ch * 8]);
        }
    }
}

// Final agg + softmax (input T3 [n][40] fp16).
__global__ __launch_bounds__(256) void agg_sm_kernel(const __half* __restrict__ Tp, const float* __restrict__ dinv,
                                                     const int* __restrict__ rowbeg, const int* __restrict__ rowend,
                                                     const int* __restrict__ adj,
                                                     const float* __restrict__ bias, float* __restrict__ out, int n) {
    constexpr int CHS = 5;
    const int tid = threadIdx.x;
    const int c = tid & 7;
    const int d = (int)((blockIdx.x * 256 + tid) >> 3);
    if (d >= n) return;
    const bool act = (c < CHS);
    const int cc = act ? c : (CHS - 1);
    const uint4* Tp4 = reinterpret_cast<const uint4*>(Tp);

    __half2 a0 = __float2half2_rn(0.f), a1 = a0, a2 = a0, a3 = a0;
    __half2 c0 = a0, c1 = a0, c2 = a0, c3 = a0;
    const int beg = rowbeg[d], end = rowend[d];
    int e0 = beg;
    for (; e0 + 8 <= end; e0 += 8) {
        const int myadj = adj[e0 + c];
        uint4 r[8];
        #pragma unroll
        for (int j = 0; j < 8; ++j) {
            const int s = __shfl(myadj, j, 8);
            r[j] = Tp4[(long)s * CHS + cc];
        }
        accum_row(r[0], a0, a1, a2, a3);
        accum_row(r[1], c0, c1, c2, c3);
        accum_row(r[2], a0, a1, a2, a3);
        accum_row(r[3], c0, c1, c2, c3);
        accum_row(r[4], a0, a1, a2, a3);
        accum_row(r[5], c0, c1, c2, c3);
        accum_row(r[6], a0, a1, a2, a3);
        accum_row(r[7], c0, c1, c2, c3);
    }
    if (e0 < end) {
        const int last = end - 1;
        const int idx = e0 + c;
        const int myadj = adj[idx <= last ? idx : last];
        uint4 r[8];
        #pragma unroll
        for (int j = 0; j < 8; ++j) {
            const int s = __shfl(myadj, j, 8);
            r[j] = Tp4[(long)s * CHS + cc];
        }
        #pragma unroll
        for (int j = 0; j < 8; ++j) {
            if (e0 + j <= last) {
                if (j & 1) accum_row(r[j], c0, c1, c2, c3);
                else       accum_row(r[j], a0, a1, a2, a3);
            }
        }
    }

    float vals[8];
    if (act) {
        const uint4 sraw = Tp4[(long)d * CHS + c];
        const __half2* sh = reinterpret_cast<const __half2*>(&sraw);
        a0 = __hadd2(__hadd2(a0, c0), sh[0]);
        a1 = __hadd2(__hadd2(a1, c1), sh[1]);
        a2 = __hadd2(__hadd2(a2, c2), sh[2]);
        a3 = __hadd2(__hadd2(a3, c3), sh[3]);
        const float di = dinv[d];
        const float4 b0 = *reinterpret_cast<const float4*>(&bias[c * 8]);
        const float4 b1 = *reinterpret_cast<const float4*>(&bias[c * 8 + 4]);
        const float2 f0 = __half22float2(a0), f1 = __half22float2(a1);
        const float2 f2 = __half22float2(a2), f3 = __half22float2(a3);
        vals[0] = f0.x * di + b0.x; vals[1] = f0.y * di + b0.y;
        vals[2] = f1.x * di + b0.z; vals[3] = f1.y * di + b0.w;
        vals[4] = f2.x * di + b1.x; vals[5] = f2.y * di + b1.y;
        vals[6] = f3.x * di + b1.z; vals[7] = f3.y * di + b1.w;
    }
    float mx = -1e30f;
    if (act) {
        #pragma unroll
        for (int j = 0; j < 8; ++j) mx = fmaxf(mx, vals[j]);
    }
    #pragma unroll
    for (int off = 1; off <= 4; off <<= 1) mx = fmaxf(mx, __shfl_xor(mx, off, 8));
    float e8[8];
    float sum = 0.f;
    if (act) {
        #pragma unroll
        for (int j = 0; j < 8; ++j) { e8[j] = expf(vals[j] - mx); sum += e8[j]; }
    }
    #pragma unroll
    for (int off = 1; off <= 4; off <<= 1) sum += __shfl_xor(sum, off, 8);
    if (act) {
        const float inv = 1.0f / sum;
        const float4 o0 = make_float4(e8[0] * inv, e8[1] * inv, e8[2] * inv, e8[3] * inv);
        const float4 o1 = make_float4(e8[4] * inv, e8[5] * inv, e8[6] * inv, e8[7] * inv);
        *reinterpret_cast<float4*>(&out[(long)d * 40 + c * 8]) = o0;
        *reinterpret_cast<float4*>(&out[(long)d * 40 + c * 8 + 4]) = o1;
    }
}

extern "C" void kernel_launch(void* const* d_in, const int* in_sizes, int n_in,
                              void* d_out, int out_size, void* d_ws, size_t ws_size,
                              hipStream_t stream) {
    const float* x  = (const float*)d_in[0];
    const int*   ei = (const int*)d_in[1];
    const float* W0 = (const float*)d_in[2];
    const float* b0 = (const float*)d_in[3];
    const float* W1 = (const float*)d_in[4];
    const float* b1 = (const float*)d_in[5];
    const float* W2 = (const float*)d_in[6];
    const float* b2 = (const float*)d_in[7];
    const float* W3 = (const float*)d_in[8];
    const float* b3 = (const float*)d_in[9];

    const int N = in_sizes[0] / 128;
    const int E = in_sizes[1] / 2;
    const int* src = ei;
    const int* dst = ei + E;

    const int nBuck = (N + BSIZE - 1) >> BBITS;   // 196

    char* ws = (char*)d_ws;
    auto align256 = [](size_t v) { return (v + 255) & ~(size_t)255; };
    size_t o = 0;
    int*    gCursor    = (int*)(ws + o);    o += align256(256 * 4);
    int*    rowbeg     = (int*)(ws + o);    o += align256((size_t)N * 4);
    int*    rowend     = (int*)(ws + o);    o += align256((size_t)N * 4);
    float*  dinv       = (float*)(ws + o);  o += align256((size_t)N * 4);
    int*    adj        = (int*)(ws + o);    o += align256((size_t)nBuck * BCAP * 4);
    __half* Wt0        = (__half*)(ws + o); o += align256(64 * 128 * 2);
    __half* Wt1        = (__half*)(ws + o); o += align256(64 * 64 * 2);
    __half* Wt2        = (__half*)(ws + o); o += align256(64 * 64 * 2);
    __half* Wt3        = (__half*)(ws + o); o += align256(48 * 64 * 2);
    __half* T          = (__half*)(ws + o); o += align256((size_t)N * 64 * 2);
    __half* B          = (__half*)(ws + o); o += align256((size_t)N * 64 * 2);
    unsigned* pairbuf  = (unsigned*)T;      // alias: 8.0 MB <= 12.8 MB; consumed before gemm0 writes T
    float* OUT         = (float*)d_out;

    const int nb_gemm0 = (N + 63) / 64;
    const int nb_fused = (N + 31) / 32;
    const int nb_aggsm = (N * 8 + 255) / 256;
    const int nb_passA = (E + CHUNK - 1) / CHUNK;

    // Build CSR + dinv + fp16 weights (memset + 2 dispatches)
    hipMemsetAsync(gCursor, 0, 1024, stream);
    passA_kernel<<<nb_passA + 4, 256, 0, stream>>>(src, dst, gCursor, pairbuf, E, nb_passA,
                                                   W0, W1, W2, W3, Wt0, Wt1, Wt2, Wt3);
    passB_kernel<<<nBuck, 256, 0, stream>>>(pairbuf, gCursor, rowbeg, rowend, dinv, adj, N);

    // Layer 0 GEMM: x -> T (= T'_1)
    gemm0_kernel<<<nb_gemm0, 256, 0, stream>>>(x, Wt0, dinv, T, N);
    // Fused layers: agg + leaky + gemm_{l+1}
    agg_gemm_kernel<64><<<nb_fused, 256, 0, stream>>>(T, dinv, rowbeg, rowend, adj, b0, Wt1, B, N);  // -> T'_2
    agg_gemm_kernel<64><<<nb_fused, 256, 0, stream>>>(B, dinv, rowbeg, rowend, adj, b1, Wt2, T, N);  // -> T'_3
    agg_gemm_kernel<48><<<nb_fused, 256, 0, stream>>>(T, dinv, rowbeg, rowend, adj, b2, Wt3, B, N);  // -> T3 [N][40]
    // Final agg + softmax
    agg_sm_kernel<<<nb_aggsm, 256, 0, stream>>>(B, dinv, rowbeg, rowend, adj, b3, OUT, N);
}